// Round 16
// baseline (267.975 us; speedup 1.0000x reference)
//
#include <hip/hip_runtime.h>
#include <hip/hip_bf16.h>
#include <stdint.h>

#define SQ 4096
#define DM 1280
#define NH 16
#define HDIM 80
#define N_QKV 3840

typedef __attribute__((ext_vector_type(8))) short short8;
typedef __attribute__((ext_vector_type(4))) float f32x4;

__device__ __forceinline__ unsigned short f2bf(float f) {
  union { float f; unsigned int u; } v; v.f = f;
  unsigned int r = v.u + 0x7FFFu + ((v.u >> 16) & 1u);
  return (unsigned short)(r >> 16);
}
__device__ __forceinline__ float bf2f(unsigned short u) {
  union { unsigned int u; float f; } v; v.u = ((unsigned int)u) << 16;
  return v.f;
}

// One fused convert pass over hidden (5120 blk), qkv_w (4800 blk), proj_w (1600 blk)
__global__ __launch_bounds__(256) void cvt_all(const float* __restrict__ hidden,
                                               const float* __restrict__ qkv_w,
                                               const float* __restrict__ proj_w,
                                               unsigned short* __restrict__ oh,
                                               unsigned short* __restrict__ oq,
                                               unsigned short* __restrict__ op) {
  int b = blockIdx.x;
  const float* in;
  unsigned short* out;
  int base;
  if (b < 5120) { in = hidden; out = oh; base = b; }
  else if (b < 9920) { in = qkv_w; out = oq; base = b - 5120; }
  else { in = proj_w; out = op; base = b - 9920; }
  int i = base * 256 + threadIdx.x;
  float4 v = reinterpret_cast<const float4*>(in)[i];
  ushort4 o;
  o.x = f2bf(v.x); o.y = f2bf(v.y); o.z = f2bf(v.z); o.w = f2bf(v.w);
  reinterpret_cast<ushort4*>(out)[i] = o;
}

__device__ __forceinline__ void gload_lds16(const void* g, void* l) {
  __builtin_amdgcn_global_load_lds(
      (const __attribute__((address_space(1))) void*)g,
      (__attribute__((address_space(3))) void*)l, 16, 0, 0);
}

// C[M][N] = A[M][K](bf16) * B[N][K]^T(bf16) + bias. 256x128 tiles, 8 waves
// (4M x 2N, 64x64 per wave). 3-buffer depth-2 prefetch, counted vmcnt,
// raw barriers. XCD rectangle remap (16 row-tiles = 4 bands of 4).
template <int OUT_BF16>
__global__ __launch_bounds__(512, 4) void gemm_bt2(const unsigned short* __restrict__ A,
                                                   const unsigned short* __restrict__ B,
                                                   const float* __restrict__ bias,
                                                   void* __restrict__ C, int M, int N, int K,
                                                   int nbx) {
  __shared__ __align__(16) unsigned short As[3][256 * 32];
  __shared__ __align__(16) unsigned short Bs[3][128 * 32];
  const int tid = threadIdx.x;
  const int wave = tid >> 6, lane = tid & 63;
  const int r15 = lane & 15, kg = lane >> 4;
  const int wr = wave >> 1, wc = wave & 1;   // 4M x 2N wave grid

  const int b = blockIdx.x;
  const int c = b & 7, i = b >> 3;
  const int by = (c & 3) * 4 + (i & 3);            // 16 row tiles: 4 bands of 4
  const int bx = (c >> 2) * (nbx >> 1) + (i >> 2); // col bands
  const int tm = by * 256, tn = bx * 128;

  f32x4 acc[4][4];
#pragma unroll
  for (int x = 0; x < 4; ++x)
#pragma unroll
    for (int j = 0; j < 4; ++j) acc[x][j] = {0.f, 0.f, 0.f, 0.f};

  // staging geometry: A = 1024 chunks (2/thread), B = 512 chunks (1/thread)
  const int rowt = tid >> 2, k8t = (tid & 3) << 3;
  const unsigned short* Arow0 = A + (size_t)(tm + rowt) * K + k8t;
  const unsigned short* Arow1 = Arow0 + (size_t)128 * K;     // chunk 512+tid
  const unsigned short* Brow = B + (size_t)(tn + rowt) * K + k8t;
  const int ldsA0 = tid * 8, ldsA1 = (512 + tid) * 8, ldsB = tid * 8;

  auto stage = [&](int kt, int buf) {
    gload_lds16(Arow0 + kt, &As[buf][ldsA0]);
    gload_lds16(Arow1 + kt, &As[buf][ldsA1]);
    gload_lds16(Brow + kt, &Bs[buf][ldsB]);
  };

  const int nk = K >> 5;
  stage(0, 0);
  stage(32, 1);

  int buf = 0;
  for (int t = 0; t < nk; ++t) {
    if (t + 2 < nk) {
      stage((t + 2) << 5, (buf + 2) % 3);
      asm volatile("s_waitcnt vmcnt(6)" ::: "memory");  // tile t landed
    } else if (t + 1 < nk) {
      asm volatile("s_waitcnt vmcnt(3)" ::: "memory");
    } else {
      asm volatile("s_waitcnt vmcnt(0)" ::: "memory");
    }
    __builtin_amdgcn_sched_barrier(0);
    __builtin_amdgcn_s_barrier();

    short8 af[4], bfr[4];
#pragma unroll
    for (int mi = 0; mi < 4; ++mi)
      af[mi] = *reinterpret_cast<const short8*>(&As[buf][(wr * 64 + mi * 16 + r15) * 32 + kg * 8]);
#pragma unroll
    for (int ni = 0; ni < 4; ++ni)
      bfr[ni] = *reinterpret_cast<const short8*>(&Bs[buf][(wc * 64 + ni * 16 + r15) * 32 + kg * 8]);
    __builtin_amdgcn_s_setprio(1);
#pragma unroll
    for (int mi = 0; mi < 4; ++mi)
#pragma unroll
      for (int ni = 0; ni < 4; ++ni)
        acc[mi][ni] = __builtin_amdgcn_mfma_f32_16x16x32_bf16(af[mi], bfr[ni], acc[mi][ni], 0, 0, 0);
    __builtin_amdgcn_s_setprio(0);

    __builtin_amdgcn_s_barrier();
    __builtin_amdgcn_sched_barrier(0);
    buf = (buf + 1) % 3;
  }

#pragma unroll
  for (int mi = 0; mi < 4; ++mi) {
#pragma unroll
    for (int ni = 0; ni < 4; ++ni) {
      int col = tn + wc * 64 + ni * 16 + r15;
      float bv = bias[col];
#pragma unroll
      for (int r = 0; r < 4; ++r) {
        int row = tm + wr * 64 + mi * 16 + kg * 4 + r;
        float v = acc[mi][ni][r] + bv;
        if (OUT_BF16)
          ((unsigned short*)C)[(size_t)row * N + col] = f2bf(v);
        else
          ((float*)C)[(size_t)row * N + col] = v;
      }
    }
  }
}

// In-place RoPE on q,k columns of qkv[s][3840]; q additionally pre-scaled by
// 1/sqrt(80); transpose v into Vt[h][d][s].
__global__ __launch_bounds__(256) void rope_v_kernel(unsigned short* __restrict__ qkv,
                                                     const float* __restrict__ cosb,
                                                     const float* __restrict__ sinb,
                                                     unsigned short* __restrict__ Vt) {
  const float SC = 0.1118033988749895f;  // 1/sqrt(80)
  int h = blockIdx.y, s0 = blockIdx.x * 64;
  __shared__ unsigned short vt[64][80];
  for (int e = threadIdx.x; e < 64 * 40; e += 256) {
    int sl = e / 40, dp = e % 40;
    int s = s0 + sl;
    float c = cosb[s * HDIM + dp];
    float sn = sinb[s * HDIM + dp];
    size_t qb = (size_t)s * N_QKV + h * HDIM;
    float q1 = bf2f(qkv[qb + dp]), q2 = bf2f(qkv[qb + dp + 40]);
    qkv[qb + dp] = f2bf((q1 * c - q2 * sn) * SC);
    qkv[qb + dp + 40] = f2bf((q2 * c + q1 * sn) * SC);
    size_t kb = qb + DM;
    float k1 = bf2f(qkv[kb + dp]), k2 = bf2f(qkv[kb + dp + 40]);
    qkv[kb + dp] = f2bf(k1 * c - k2 * sn);
    qkv[kb + dp + 40] = f2bf(k2 * c + k1 * sn);
    size_t vb = qb + 2 * DM;
    vt[sl][dp] = qkv[vb + dp];
    vt[sl][dp + 40] = qkv[vb + dp + 40];
  }
  __syncthreads();
  for (int e = threadIdx.x; e < HDIM * 64; e += 256) {
    int d = e >> 6, sl = e & 63;
    Vt[((size_t)h * HDIM + d) * SQ + s0 + sl] = vt[sl][d];
  }
}

// ---- DPP 16-lane row reductions (VALU, no LDS) ----
template <int CTRL>
__device__ __forceinline__ float dpp_f(float x) {
  int xi = __builtin_bit_cast(int, x);
  int r = __builtin_amdgcn_update_dpp(xi, xi, CTRL, 0xf, 0xf, true);
  return __builtin_bit_cast(float, r);
}
__device__ __forceinline__ float rowmax16(float x) {
  x = fmaxf(x, dpp_f<0xB1>(x));    // quad_perm [1,0,3,2]
  x = fmaxf(x, dpp_f<0x4E>(x));    // quad_perm [2,3,0,1]
  x = fmaxf(x, dpp_f<0x141>(x));   // row_half_mirror
  x = fmaxf(x, dpp_f<0x140>(x));   // row_mirror
  return x;
}
__device__ __forceinline__ float rowsum16(float x) {
  x += dpp_f<0xB1>(x);
  x += dpp_f<0x4E>(x);
  x += dpp_f<0x141>(x);
  x += dpp_f<0x140>(x);
  return x;
}

// Flash attention, block-diagonal mask — round-15 structure (K+V swizzled LDS
// dbuf, ordered VMEM stream, counted vmcnt, two raw barriers, lean softmax,
// LPT ordering) with LDS shrunk for 3 blocks/CU (+50% TLP):
//   K rows 192B (chunk ^= row&3 swizzle; 4-way read conflict accepted)
//   P relayout PROW=64 XOR-swizzled (verified rounds 7-9)
// LDS ~52.4KB -> 3 blocks/CU. 6 VMEM issues/tile -> vmcnt(6).
__global__ __launch_bounds__(256, 3) void attn_kernel(const unsigned short* __restrict__ qkv,
                                                      const unsigned short* __restrict__ Vt,
                                                      const int* __restrict__ cu, int nseg,
                                                      unsigned short* __restrict__ attn_out) {
  __shared__ __align__(16) unsigned char Kl[2][64 * 192];    // 24576 B
  __shared__ __align__(16) unsigned char Vl[2][80 * 128];    // 20480 B
  __shared__ __align__(16) unsigned short Pl[4][16 * 64];    //  8192 B
  __shared__ int cus[32];
  __shared__ int keyv[64];
  __shared__ unsigned char tile_of_rank[64];

  const int tid = threadIdx.x;
  const int wave = tid >> 6, lane = tid & 63;
  const int r15 = lane & 15, kg = lane >> 4;
  const int s7 = r15 & 7;
  const int s3 = r15 & 3;
  const short8 z8 = {0, 0, 0, 0, 0, 0, 0, 0};

  const int b = blockIdx.x;
  const int xcd = b & 7, j = b >> 3;       // j in 0..127
  const int h = xcd * 2 + (j >> 6);

  if (tid <= nseg) cus[tid] = cu[tid];
  __syncthreads();

  auto seg_of = [&](int pos) {
    int s2 = 0;
    for (int i2 = 1; i2 < nseg; ++i2)
      if (pos >= cus[i2]) s2 = i2;
    return s2;
  };

  // ---- LPT remap: rank 64 q-tiles by descending nt ----
  if (tid < 64) {
    int tb = tid * 64;
    int kb = cus[seg_of(tb)] & ~63;
    int ke = cus[seg_of(tb + 63) + 1];
    keyv[tid] = (ke - kb + 63) >> 6;
  }
  __syncthreads();
  if (tid < 64) {
    int mykey = keyv[tid];
    int rank = 0;
    for (int u = 0; u < 64; ++u) {
      int ku = keyv[u];
      rank += (ku > mykey) || (ku == mykey && u < tid);
    }
    tile_of_rank[rank] = (unsigned char)tid;
  }
  __syncthreads();
  const int qt = tile_of_rank[j & 63];

  const int tbase = qt * 64;
  const int wbase = tbase + wave * 16;
  int rs[4], re[4];
#pragma unroll
  for (int r = 0; r < 4; ++r) {
    int sg = seg_of(wbase + kg * 4 + r);
    rs[r] = cus[sg];
    re[r] = cus[sg + 1];
  }
  const int seg_lo = seg_of(wbase), seg_hi = seg_of(wbase + 15);
  const int w_lo = cus[seg_lo], w_hi = cus[seg_hi + 1];
  const int rs_hi = cus[seg_hi], re_lo = cus[seg_lo + 1];

  const int kb0 = cus[seg_of(tbase)] & ~63;
  const int kend = cus[seg_of(tbase + 63) + 1];
  const int nt = (kend - kb0 + 63) >> 6;

  const unsigned short* qp = qkv + (size_t)(wbase + r15) * N_QKV + h * HDIM;
  short8 qf[3];
#pragma unroll
  for (int ds = 0; ds < 3; ++ds) {
    int d0 = ds * 32 + kg * 8;
    qf[ds] = (d0 < HDIM) ? *reinterpret_cast<const short8*>(qp + d0) : z8;
  }

  float m[4] = {-1e30f, -1e30f, -1e30f, -1e30f};
  float l[4] = {0.f, 0.f, 0.f, 0.f};
  f32x4 acc[5];
#pragma unroll
  for (int dg = 0; dg < 5; ++dg) acc[dg] = {0.f, 0.f, 0.f, 0.f};

  const unsigned short* kbase = qkv + DM + (size_t)h * HDIM;
  const unsigned short* vbase = Vt + (size_t)h * HDIM * SQ;
  unsigned short* pw = &Pl[wave][0];
  const int wub = tid & ~63;  // wave*64

  // K staging geometry: 768 chunks of 16B (64 rows x 12 chunks), 3 passes.
  // Physical chunk P = p*256+tid -> row=P/12, pc=P%12; logical c = pc^(row&3);
  // pad logical chunks 10,11 load dummy (never read). Precompute per-thread.
  int krow[3], kcs[3];
#pragma unroll
  for (int p = 0; p < 3; ++p) {
    int P = p * 256 + tid;
    int row = P / 12, pc = P - row * 12;
    int c = pc ^ (row & 3);
    krow[p] = row;
    kcs[p] = (c < 10) ? c : 0;
  }

  // 6 VMEM issues per wave per tile: K 3 + V 2 + V tail (exec-masked, still 1).
  auto issue_stage = [&](int kb, int buf) {
    unsigned char* kd = &Kl[buf][0];
    unsigned char* vd = &Vl[buf][0];
#pragma unroll
    for (int p = 0; p < 3; ++p)
      gload_lds16(kbase + (size_t)(kb + krow[p]) * N_QKV + kcs[p] * 8,
                  kd + (p * 256 + wub) * 16);
#pragma unroll
    for (int p = 0; p < 2; ++p) {            // V: first 512 of 640 chunks
      int L = p * 256 + tid;
      int row = L >> 3;
      int c = (L & 7) ^ (row & 7);
      gload_lds16(vbase + (size_t)row * SQ + kb + c * 8,
                  vd + (p * 256 + wub) * 16);
    }
    {                                        // V: last 128 chunks, 32 lanes/wave
      int L = 512 + (wub >> 1) + (lane & 31);
      int row = L >> 3;
      int c = (L & 7) ^ (row & 7);
      if (lane < 32)
        gload_lds16(vbase + (size_t)row * SQ + kb + c * 8,
                    vd + (512 + (wub >> 1)) * 16);
    }
  };

  issue_stage(kb0, 0);
  int cur = 0;

  for (int t = 0; t < nt; ++t) {
    const int k0 = kb0 + (t << 6);
    if (t + 1 < nt) {
      issue_stage(k0 + 64, cur ^ 1);
      asm volatile("s_waitcnt vmcnt(6)" ::: "memory");  // tile t landed; t+1 in flight
    } else {
      asm volatile("s_waitcnt vmcnt(0)" ::: "memory");
    }
    __builtin_amdgcn_sched_barrier(0);
    __builtin_amdgcn_s_barrier();            // raw: no compiler vmcnt(0) drain

    const bool active = (k0 < w_hi) && (k0 + 64 > w_lo);
    if (active) {
      const unsigned char* Kc = &Kl[cur][0];
      const unsigned char* Vc = &Vl[cur][0];

      // ---- QK^T from swizzled LDS (192B rows; chunk = (ds*4+kg)^(r15&3)) ----
      f32x4 sa[4];
#pragma unroll
      for (int g = 0; g < 4; ++g) sa[g] = {0.f, 0.f, 0.f, 0.f};
#pragma unroll
      for (int g = 0; g < 4; ++g) {
        const unsigned char* kr = Kc + (g * 16 + r15) * 192;
#pragma unroll
        for (int ds = 0; ds < 3; ++ds) {
          int d0 = ds * 32 + kg * 8;
          short8 kf = (d0 < HDIM)
              ? *reinterpret_cast<const short8*>(kr + (((ds * 4 + kg) ^ s3) << 4))
              : z8;
          sa[g] = __builtin_amdgcn_mfma_f32_16x16x32_bf16(qf[ds], kf, sa[g], 0, 0, 0);
        }
      }

      short8 vf[5][2];
#pragma unroll
      for (int dg = 0; dg < 5; ++dg)
#pragma unroll
        for (int g2 = 0; g2 < 2; ++g2)
          vf[dg][g2] = *reinterpret_cast<const short8*>(
              Vc + ((dg * 16 + r15) << 7) + (((g2 * 4 + kg) ^ s7) << 4));

      // ---- lean online softmax (P-write swizzled, PROW=64) ----
      const bool interior = (k0 >= rs_hi) && (k0 + 64 <= re_lo);
      float corr[4];
      bool resc;
      if (interior) {
        float mx4[4];
#pragma unroll
        for (int r = 0; r < 4; ++r)
          mx4[r] = rowmax16(fmaxf(fmaxf(sa[0][r], sa[1][r]), fmaxf(sa[2][r], sa[3][r])));
        int defer = (mx4[0] <= m[0] + 8.f) && (mx4[1] <= m[1] + 8.f) &&
                    (mx4[2] <= m[2] + 8.f) && (mx4[3] <= m[3] + 8.f);
        if (__all(defer)) {
          resc = false;
#pragma unroll
          for (int r = 0; r < 4; ++r) {
            int row = kg * 4 + r, rsw = row & 7;
            unsigned short* prow = pw + row * 64;
            float sm = 0.f;
#pragma unroll
            for (int g = 0; g < 4; ++g) {
              float pv = __expf(sa[g][r] - m[r]);
              sm += pv;
              prow[(((g * 2 + (r15 >> 3)) ^ rsw) << 3) + (r15 & 7)] = f2bf(pv);
            }
            l[r] += rowsum16(sm);
          }
        } else {
          resc = true;
#pragma unroll
          for (int r = 0; r < 4; ++r) {
            int row = kg * 4 + r, rsw = row & 7;
            unsigned short* prow = pw + row * 64;
            float mn = fmaxf(m[r], mx4[r]);
            corr[r] = __expf(m[r] - mn);
            float sm = 0.f;
#pragma unroll
            for (int g = 0; g < 4; ++g) {
              float pv = __expf(sa[g][r] - mn);
              sm += pv;
              prow[(((g * 2 + (r15 >> 3)) ^ rsw) << 3) + (r15 & 7)] = f2bf(pv);
            }
            l[r] = l[r] * corr[r] + rowsum16(sm);
            m[r] = mn;
          }
        }
      } else {
        resc = true;
#pragma unroll
        for (int r = 0; r < 4; ++r) {
          int row = kg * 4 + r, rsw = row & 7;
          unsigned short* prow = pw + row * 64;
          float vv[4];
#pragma unroll
          for (int g = 0; g < 4; ++g) {
            int key = k0 + g * 16 + r15;
            vv[g] = (key >= rs[r] && key < re[r]) ? sa[g][r] : -1e30f;
          }
          float mx = rowmax16(fmaxf(fmaxf(vv[0], vv[1]), fmaxf(vv[2], vv[3])));
          float mn = fmaxf(m[r], mx);
          corr[r] = __expf(m[r] - mn);
          float sm = 0.f;
#pragma unroll
          for (int g = 0; g < 4; ++g) {
            float pv = __expf(vv[g] - mn);
            sm += pv;
            prow[(((g * 2 + (r15 >> 3)) ^ rsw) << 3) + (r15 & 7)] = f2bf(pv);
          }
          l[r] = l[r] * corr[r] + rowsum16(sm);
          m[r] = mn;
        }
      }
      if (resc) {
#pragma unroll
        for (int dg = 0; dg < 5; ++dg) {
          f32x4 t2 = acc[dg];
          t2[0] *= corr[0]; t2[1] *= corr[1]; t2[2] *= corr[2]; t2[3] *= corr[3];
          acc[dg] = t2;
        }
      }

      // ---- P (D-frag) -> A-frag via swizzled wave-private LDS (b128 read) ----
      asm volatile("s_waitcnt lgkmcnt(0)" ::: "memory");
      __builtin_amdgcn_sched_barrier(0);
      short8 pu[2];
#pragma unroll
      for (int g2 = 0; g2 < 2; ++g2)
        pu[g2] = *reinterpret_cast<const short8*>(
            pw + r15 * 64 + (((g2 * 4 + kg) ^ s7) << 3));

      // ---- PV ----
      __builtin_amdgcn_s_setprio(1);
#pragma unroll
      for (int dg = 0; dg < 5; ++dg)
#pragma unroll
        for (int g2 = 0; g2 < 2; ++g2)
          acc[dg] = __builtin_amdgcn_mfma_f32_16x16x32_bf16(pu[g2], vf[dg][g2], acc[dg], 0, 0, 0);
      __builtin_amdgcn_s_setprio(0);
    }

    __builtin_amdgcn_s_barrier();            // all waves done reading buf[cur]
    cur ^= 1;
  }

  // epilogue
#pragma unroll
  for (int r = 0; r < 4; ++r) {
    int row = wbase + kg * 4 + r;
    float inv = 1.0f / l[r];
#pragma unroll
    for (int dg = 0; dg < 5; ++dg)
      attn_out[(size_t)row * DM + h * HDIM + dg * 16 + r15] = f2bf(acc[dg][r] * inv);
  }
}

extern "C" void kernel_launch(void* const* d_in, const int* in_sizes, int n_in,
                              void* d_out, int out_size, void* d_ws, size_t ws_size,
                              hipStream_t stream) {
  const float* hidden = (const float*)d_in[0];
  const float* cosb = (const float*)d_in[1];
  const float* sinb = (const float*)d_in[2];
  const float* qkv_w = (const float*)d_in[3];
  const float* qkv_b = (const float*)d_in[4];
  const float* proj_w = (const float*)d_in[5];
  const float* proj_b = (const float*)d_in[6];
  const int* cu = (const int*)d_in[7];
  int nseg = in_sizes[7] - 1;
  float* out = (float*)d_out;

  char* ws = (char*)d_ws;
  unsigned short* Ah = (unsigned short*)(ws);                        // 10,485,760 B
  unsigned short* Wq = (unsigned short*)(ws + 10485760);             //  9,830,400 B
  unsigned short* Wp = (unsigned short*)(ws + 10485760 + 9830400);   //  3,276,800 B
  unsigned short* qkvB = (unsigned short*)(ws + 23592960);           // 31,457,280 B
  unsigned short* Vt = (unsigned short*)(ws + 23592960 + 31457280);  // 10,485,760 B
  unsigned short* attn_out = Ah;  // reuse (Ah dead after GEMM1)

  cvt_all<<<dim3(11520), dim3(256), 0, stream>>>(hidden, qkv_w, proj_w, Ah, Wq, Wp);
  gemm_bt2<1><<<dim3(480), dim3(512), 0, stream>>>(Ah, Wq, qkv_b, qkvB, SQ, N_QKV, DM, 30);
  rope_v_kernel<<<dim3(64, NH), dim3(256), 0, stream>>>(qkvB, cosb, sinb, Vt);
  attn_kernel<<<dim3(1024), dim3(256), 0, stream>>>(qkvB, Vt, cu, nseg, attn_out);
  gemm_bt2<0><<<dim3(160), dim3(512), 0, stream>>>(attn_out, Wp, proj_b, out, SQ, DM, DM, 10);
}

// Round 17
// 173.913 us; speedup vs baseline: 1.5409x; 1.5409x over previous
//
#include <hip/hip_runtime.h>
#include <hip/hip_bf16.h>
#include <stdint.h>

#define SQ 4096
#define DM 1280
#define NH 16
#define HDIM 80
#define N_QKV 3840

typedef __attribute__((ext_vector_type(8))) short short8;
typedef __attribute__((ext_vector_type(4))) float f32x4;

__device__ __forceinline__ unsigned short f2bf(float f) {
  union { float f; unsigned int u; } v; v.f = f;
  unsigned int r = v.u + 0x7FFFu + ((v.u >> 16) & 1u);
  return (unsigned short)(r >> 16);
}
__device__ __forceinline__ float bf2f(unsigned short u) {
  union { unsigned int u; float f; } v; v.u = ((unsigned int)u) << 16;
  return v.f;
}

// One fused convert pass over hidden (5120 blk), qkv_w (4800 blk), proj_w (1600 blk)
__global__ __launch_bounds__(256) void cvt_all(const float* __restrict__ hidden,
                                               const float* __restrict__ qkv_w,
                                               const float* __restrict__ proj_w,
                                               unsigned short* __restrict__ oh,
                                               unsigned short* __restrict__ oq,
                                               unsigned short* __restrict__ op) {
  int b = blockIdx.x;
  const float* in;
  unsigned short* out;
  int base;
  if (b < 5120) { in = hidden; out = oh; base = b; }
  else if (b < 9920) { in = qkv_w; out = oq; base = b - 5120; }
  else { in = proj_w; out = op; base = b - 9920; }
  int i = base * 256 + threadIdx.x;
  float4 v = reinterpret_cast<const float4*>(in)[i];
  ushort4 o;
  o.x = f2bf(v.x); o.y = f2bf(v.y); o.z = f2bf(v.z); o.w = f2bf(v.w);
  reinterpret_cast<ushort4*>(out)[i] = o;
}

__device__ __forceinline__ void gload_lds16(const void* g, void* l) {
  __builtin_amdgcn_global_load_lds(
      (const __attribute__((address_space(1))) void*)g,
      (__attribute__((address_space(3))) void*)l, 16, 0, 0);
}

// C[M][N] = A[M][K](bf16) * B[N][K]^T(bf16) + bias. 256x128 tiles, 8 waves
// (4M x 2N, 64x64 per wave). 3-buffer depth-2 prefetch, counted vmcnt,
// raw barriers. XCD rectangle remap (16 row-tiles = 4 bands of 4).
template <int OUT_BF16>
__global__ __launch_bounds__(512, 4) void gemm_bt2(const unsigned short* __restrict__ A,
                                                   const unsigned short* __restrict__ B,
                                                   const float* __restrict__ bias,
                                                   void* __restrict__ C, int M, int N, int K,
                                                   int nbx) {
  __shared__ __align__(16) unsigned short As[3][256 * 32];
  __shared__ __align__(16) unsigned short Bs[3][128 * 32];
  const int tid = threadIdx.x;
  const int wave = tid >> 6, lane = tid & 63;
  const int r15 = lane & 15, kg = lane >> 4;
  const int wr = wave >> 1, wc = wave & 1;   // 4M x 2N wave grid

  const int b = blockIdx.x;
  const int c = b & 7, i = b >> 3;
  const int by = (c & 3) * 4 + (i & 3);            // 16 row tiles: 4 bands of 4
  const int bx = (c >> 2) * (nbx >> 1) + (i >> 2); // col bands
  const int tm = by * 256, tn = bx * 128;

  f32x4 acc[4][4];
#pragma unroll
  for (int x = 0; x < 4; ++x)
#pragma unroll
    for (int j = 0; j < 4; ++j) acc[x][j] = {0.f, 0.f, 0.f, 0.f};

  // staging geometry: A = 1024 chunks (2/thread), B = 512 chunks (1/thread)
  const int rowt = tid >> 2, k8t = (tid & 3) << 3;
  const unsigned short* Arow0 = A + (size_t)(tm + rowt) * K + k8t;
  const unsigned short* Arow1 = Arow0 + (size_t)128 * K;     // chunk 512+tid
  const unsigned short* Brow = B + (size_t)(tn + rowt) * K + k8t;
  const int ldsA0 = tid * 8, ldsA1 = (512 + tid) * 8, ldsB = tid * 8;

  auto stage = [&](int kt, int buf) {
    gload_lds16(Arow0 + kt, &As[buf][ldsA0]);
    gload_lds16(Arow1 + kt, &As[buf][ldsA1]);
    gload_lds16(Brow + kt, &Bs[buf][ldsB]);
  };

  const int nk = K >> 5;
  stage(0, 0);
  stage(32, 1);

  int buf = 0;
  for (int t = 0; t < nk; ++t) {
    if (t + 2 < nk) {
      stage((t + 2) << 5, (buf + 2) % 3);
      asm volatile("s_waitcnt vmcnt(6)" ::: "memory");  // tile t landed
    } else if (t + 1 < nk) {
      asm volatile("s_waitcnt vmcnt(3)" ::: "memory");
    } else {
      asm volatile("s_waitcnt vmcnt(0)" ::: "memory");
    }
    __builtin_amdgcn_sched_barrier(0);
    __builtin_amdgcn_s_barrier();

    short8 af[4], bfr[4];
#pragma unroll
    for (int mi = 0; mi < 4; ++mi)
      af[mi] = *reinterpret_cast<const short8*>(&As[buf][(wr * 64 + mi * 16 + r15) * 32 + kg * 8]);
#pragma unroll
    for (int ni = 0; ni < 4; ++ni)
      bfr[ni] = *reinterpret_cast<const short8*>(&Bs[buf][(wc * 64 + ni * 16 + r15) * 32 + kg * 8]);
    __builtin_amdgcn_s_setprio(1);
#pragma unroll
    for (int mi = 0; mi < 4; ++mi)
#pragma unroll
      for (int ni = 0; ni < 4; ++ni)
        acc[mi][ni] = __builtin_amdgcn_mfma_f32_16x16x32_bf16(af[mi], bfr[ni], acc[mi][ni], 0, 0, 0);
    __builtin_amdgcn_s_setprio(0);

    __builtin_amdgcn_s_barrier();
    __builtin_amdgcn_sched_barrier(0);
    buf = (buf + 1) % 3;
  }

#pragma unroll
  for (int mi = 0; mi < 4; ++mi) {
#pragma unroll
    for (int ni = 0; ni < 4; ++ni) {
      int col = tn + wc * 64 + ni * 16 + r15;
      float bv = bias[col];
#pragma unroll
      for (int r = 0; r < 4; ++r) {
        int row = tm + wr * 64 + mi * 16 + kg * 4 + r;
        float v = acc[mi][ni][r] + bv;
        if (OUT_BF16)
          ((unsigned short*)C)[(size_t)row * N + col] = f2bf(v);
        else
          ((float*)C)[(size_t)row * N + col] = v;
      }
    }
  }
}

// In-place RoPE on q,k columns of qkv[s][3840]; q additionally pre-scaled by
// 1/sqrt(80); transpose v into Vt[h][d][s].
__global__ __launch_bounds__(256) void rope_v_kernel(unsigned short* __restrict__ qkv,
                                                     const float* __restrict__ cosb,
                                                     const float* __restrict__ sinb,
                                                     unsigned short* __restrict__ Vt) {
  const float SC = 0.1118033988749895f;  // 1/sqrt(80)
  int h = blockIdx.y, s0 = blockIdx.x * 64;
  __shared__ unsigned short vt[64][80];
  for (int e = threadIdx.x; e < 64 * 40; e += 256) {
    int sl = e / 40, dp = e % 40;
    int s = s0 + sl;
    float c = cosb[s * HDIM + dp];
    float sn = sinb[s * HDIM + dp];
    size_t qb = (size_t)s * N_QKV + h * HDIM;
    float q1 = bf2f(qkv[qb + dp]), q2 = bf2f(qkv[qb + dp + 40]);
    qkv[qb + dp] = f2bf((q1 * c - q2 * sn) * SC);
    qkv[qb + dp + 40] = f2bf((q2 * c + q1 * sn) * SC);
    size_t kb = qb + DM;
    float k1 = bf2f(qkv[kb + dp]), k2 = bf2f(qkv[kb + dp + 40]);
    qkv[kb + dp] = f2bf(k1 * c - k2 * sn);
    qkv[kb + dp + 40] = f2bf(k2 * c + k1 * sn);
    size_t vb = qb + 2 * DM;
    vt[sl][dp] = qkv[vb + dp];
    vt[sl][dp + 40] = qkv[vb + dp + 40];
  }
  __syncthreads();
  for (int e = threadIdx.x; e < HDIM * 64; e += 256) {
    int d = e >> 6, sl = e & 63;
    Vt[((size_t)h * HDIM + d) * SQ + s0 + sl] = vt[sl][d];
  }
}

// ---- DPP 16-lane row reductions (VALU, no LDS) ----
template <int CTRL>
__device__ __forceinline__ float dpp_f(float x) {
  int xi = __builtin_bit_cast(int, x);
  int r = __builtin_amdgcn_update_dpp(xi, xi, CTRL, 0xf, 0xf, true);
  return __builtin_bit_cast(float, r);
}
__device__ __forceinline__ float rowmax16(float x) {
  x = fmaxf(x, dpp_f<0xB1>(x));    // quad_perm [1,0,3,2]
  x = fmaxf(x, dpp_f<0x4E>(x));    // quad_perm [2,3,0,1]
  x = fmaxf(x, dpp_f<0x141>(x));   // row_half_mirror
  x = fmaxf(x, dpp_f<0x140>(x));   // row_mirror
  return x;
}
__device__ __forceinline__ float rowsum16(float x) {
  x += dpp_f<0xB1>(x);
  x += dpp_f<0x4E>(x);
  x += dpp_f<0x141>(x);
  x += dpp_f<0x140>(x);
  return x;
}

// Flash attention, block-diagonal mask — round-15 verified best (74 µs):
// round-11 structure (K+V swizzled LDS dbuf, ordered VMEM stream, counted
// vmcnt(7), two raw barriers, lean softmax) + LPT block ordering.
__global__ __launch_bounds__(256, 2) void attn_kernel(const unsigned short* __restrict__ qkv,
                                                      const unsigned short* __restrict__ Vt,
                                                      const int* __restrict__ cu, int nseg,
                                                      unsigned short* __restrict__ attn_out) {
  constexpr int PROW = 68;
  __shared__ __align__(16) unsigned char Kl[2][64 * 256];    // 32768 B
  __shared__ __align__(16) unsigned char Vl[2][80 * 128];    // 20480 B
  __shared__ __align__(16) unsigned short Pl[4][16 * PROW];  //  8704 B
  __shared__ int cus[32];
  __shared__ int keyv[64];
  __shared__ unsigned char tile_of_rank[64];

  const int tid = threadIdx.x;
  const int wave = tid >> 6, lane = tid & 63;
  const int r15 = lane & 15, kg = lane >> 4;
  const int s7 = r15 & 7;
  const short8 z8 = {0, 0, 0, 0, 0, 0, 0, 0};

  const int b = blockIdx.x;
  const int xcd = b & 7, j = b >> 3;       // j in 0..127
  const int h = xcd * 2 + (j >> 6);

  if (tid <= nseg) cus[tid] = cu[tid];
  __syncthreads();

  auto seg_of = [&](int pos) {
    int s2 = 0;
    for (int i2 = 1; i2 < nseg; ++i2)
      if (pos >= cus[i2]) s2 = i2;
    return s2;
  };

  // ---- LPT remap: rank 64 q-tiles by descending nt ----
  if (tid < 64) {
    int tb = tid * 64;
    int kb = cus[seg_of(tb)] & ~63;
    int ke = cus[seg_of(tb + 63) + 1];
    keyv[tid] = (ke - kb + 63) >> 6;
  }
  __syncthreads();
  if (tid < 64) {
    int mykey = keyv[tid];
    int rank = 0;
    for (int u = 0; u < 64; ++u) {
      int ku = keyv[u];
      rank += (ku > mykey) || (ku == mykey && u < tid);
    }
    tile_of_rank[rank] = (unsigned char)tid;
  }
  __syncthreads();
  const int qt = tile_of_rank[j & 63];

  const int tbase = qt * 64;
  const int wbase = tbase + wave * 16;
  int rs[4], re[4];
#pragma unroll
  for (int r = 0; r < 4; ++r) {
    int sg = seg_of(wbase + kg * 4 + r);
    rs[r] = cus[sg];
    re[r] = cus[sg + 1];
  }
  const int seg_lo = seg_of(wbase), seg_hi = seg_of(wbase + 15);
  const int w_lo = cus[seg_lo], w_hi = cus[seg_hi + 1];
  const int rs_hi = cus[seg_hi], re_lo = cus[seg_lo + 1];

  const int kb0 = cus[seg_of(tbase)] & ~63;
  const int kend = cus[seg_of(tbase + 63) + 1];
  const int nt = (kend - kb0 + 63) >> 6;

  const unsigned short* qp = qkv + (size_t)(wbase + r15) * N_QKV + h * HDIM;
  short8 qf[3];
#pragma unroll
  for (int ds = 0; ds < 3; ++ds) {
    int d0 = ds * 32 + kg * 8;
    qf[ds] = (d0 < HDIM) ? *reinterpret_cast<const short8*>(qp + d0) : z8;
  }

  float m[4] = {-1e30f, -1e30f, -1e30f, -1e30f};
  float l[4] = {0.f, 0.f, 0.f, 0.f};
  f32x4 acc[5];
#pragma unroll
  for (int dg = 0; dg < 5; ++dg) acc[dg] = {0.f, 0.f, 0.f, 0.f};

  const unsigned short* kbase = qkv + DM + (size_t)h * HDIM;
  const unsigned short* vbase = Vt + (size_t)h * HDIM * SQ;
  unsigned short* pw = &Pl[wave][0];
  const int wub = tid & ~63;  // wave*64

  // 7 VMEM issues per wave per tile: K 4 + V 2 + V tail (exec-masked, still 1).
  auto issue_stage = [&](int kb, int buf) {
    unsigned char* kd = &Kl[buf][0];
    unsigned char* vd = &Vl[buf][0];
#pragma unroll
    for (int p = 0; p < 4; ++p) {            // K: 1024 chunks of 16B
      int L = p * 256 + tid;
      int row = L >> 4;
      int c = (L & 15) ^ (row & 7);          // inverse swizzle on global source
      int csrc = (c < 10) ? c : 0;           // pad chunks: dummy load (never read)
      gload_lds16(kbase + (size_t)(kb + row) * N_QKV + csrc * 8,
                  kd + (p * 256 + wub) * 16);
    }
#pragma unroll
    for (int p = 0; p < 2; ++p) {            // V: first 512 of 640 chunks
      int L = p * 256 + tid;
      int row = L >> 3;
      int c = (L & 7) ^ (row & 7);
      gload_lds16(vbase + (size_t)row * SQ + kb + c * 8,
                  vd + (p * 256 + wub) * 16);
    }
    {                                        // V: last 128 chunks, 32 lanes/wave
      int L = 512 + (wub >> 1) + (lane & 31);
      int row = L >> 3;
      int c = (L & 7) ^ (row & 7);
      if (lane < 32)
        gload_lds16(vbase + (size_t)row * SQ + kb + c * 8,
                    vd + (512 + (wub >> 1)) * 16);
    }
  };

  issue_stage(kb0, 0);
  int cur = 0;

  for (int t = 0; t < nt; ++t) {
    const int k0 = kb0 + (t << 6);
    if (t + 1 < nt) {
      issue_stage(k0 + 64, cur ^ 1);
      asm volatile("s_waitcnt vmcnt(7)" ::: "memory");  // tile t landed; t+1 in flight
    } else {
      asm volatile("s_waitcnt vmcnt(0)" ::: "memory");
    }
    __builtin_amdgcn_sched_barrier(0);
    __builtin_amdgcn_s_barrier();            // raw: no compiler vmcnt(0) drain

    const bool active = (k0 < w_hi) && (k0 + 64 > w_lo);
    if (active) {
      const unsigned char* Kc = &Kl[cur][0];
      const unsigned char* Vc = &Vl[cur][0];

      // ---- QK^T from swizzled LDS (Q pre-scaled; sa IS the logit) ----
      f32x4 sa[4];
#pragma unroll
      for (int g = 0; g < 4; ++g) sa[g] = {0.f, 0.f, 0.f, 0.f};
#pragma unroll
      for (int g = 0; g < 4; ++g) {
        const unsigned char* kr = Kc + ((g * 16 + r15) << 8);
#pragma unroll
        for (int ds = 0; ds < 3; ++ds) {
          int d0 = ds * 32 + kg * 8;
          short8 kf = (d0 < HDIM)
              ? *reinterpret_cast<const short8*>(kr + (((ds * 4 + kg) ^ s7) << 4))
              : z8;
          sa[g] = __builtin_amdgcn_mfma_f32_16x16x32_bf16(qf[ds], kf, sa[g], 0, 0, 0);
        }
      }

      short8 vf[5][2];
#pragma unroll
      for (int dg = 0; dg < 5; ++dg)
#pragma unroll
        for (int g2 = 0; g2 < 2; ++g2)
          vf[dg][g2] = *reinterpret_cast<const short8*>(
              Vc + ((dg * 16 + r15) << 7) + (((g2 * 4 + kg) ^ s7) << 4));

      // ---- lean online softmax ----
      const bool interior = (k0 >= rs_hi) && (k0 + 64 <= re_lo);
      float corr[4];
      bool resc;
      if (interior) {
        float mx4[4];
#pragma unroll
        for (int r = 0; r < 4; ++r)
          mx4[r] = rowmax16(fmaxf(fmaxf(sa[0][r], sa[1][r]), fmaxf(sa[2][r], sa[3][r])));
        int defer = (mx4[0] <= m[0] + 8.f) && (mx4[1] <= m[1] + 8.f) &&
                    (mx4[2] <= m[2] + 8.f) && (mx4[3] <= m[3] + 8.f);
        if (__all(defer)) {
          resc = false;
#pragma unroll
          for (int r = 0; r < 4; ++r) {
            unsigned short* prow = pw + (kg * 4 + r) * PROW;
            float sm = 0.f;
#pragma unroll
            for (int g = 0; g < 4; ++g) {
              float pv = __expf(sa[g][r] - m[r]);
              sm += pv;
              prow[g * 16 + r15] = f2bf(pv);
            }
            l[r] += rowsum16(sm);
          }
        } else {
          resc = true;
#pragma unroll
          for (int r = 0; r < 4; ++r) {
            unsigned short* prow = pw + (kg * 4 + r) * PROW;
            float mn = fmaxf(m[r], mx4[r]);
            corr[r] = __expf(m[r] - mn);
            float sm = 0.f;
#pragma unroll
            for (int g = 0; g < 4; ++g) {
              float pv = __expf(sa[g][r] - mn);
              sm += pv;
              prow[g * 16 + r15] = f2bf(pv);
            }
            l[r] = l[r] * corr[r] + rowsum16(sm);
            m[r] = mn;
          }
        }
      } else {
        resc = true;
#pragma unroll
        for (int r = 0; r < 4; ++r) {
          unsigned short* prow = pw + (kg * 4 + r) * PROW;
          float vv[4];
#pragma unroll
          for (int g = 0; g < 4; ++g) {
            int key = k0 + g * 16 + r15;
            vv[g] = (key >= rs[r] && key < re[r]) ? sa[g][r] : -1e30f;
          }
          float mx = rowmax16(fmaxf(fmaxf(vv[0], vv[1]), fmaxf(vv[2], vv[3])));
          float mn = fmaxf(m[r], mx);
          corr[r] = __expf(m[r] - mn);
          float sm = 0.f;
#pragma unroll
          for (int g = 0; g < 4; ++g) {
            float pv = __expf(vv[g] - mn);
            sm += pv;
            prow[g * 16 + r15] = f2bf(pv);
          }
          l[r] = l[r] * corr[r] + rowsum16(sm);
          m[r] = mn;
        }
      }
      if (resc) {
#pragma unroll
        for (int dg = 0; dg < 5; ++dg) {
          f32x4 t2 = acc[dg];
          t2[0] *= corr[0]; t2[1] *= corr[1]; t2[2] *= corr[2]; t2[3] *= corr[3];
          acc[dg] = t2;
        }
      }

      // ---- P (D-frag) -> A-frag via wave-private LDS ----
      asm volatile("s_waitcnt lgkmcnt(0)" ::: "memory");
      __builtin_amdgcn_sched_barrier(0);
      const unsigned short* prd = pw + r15 * PROW;
      union { short8 v; uint2 d[2]; } pu[2];
#pragma unroll
      for (int g2 = 0; g2 < 2; ++g2) {
        pu[g2].d[0] = *reinterpret_cast<const uint2*>(prd + g2 * 32 + kg * 8);
        pu[g2].d[1] = *reinterpret_cast<const uint2*>(prd + g2 * 32 + kg * 8 + 4);
      }

      // ---- PV ----
      __builtin_amdgcn_s_setprio(1);
#pragma unroll
      for (int dg = 0; dg < 5; ++dg)
#pragma unroll
        for (int g2 = 0; g2 < 2; ++g2)
          acc[dg] = __builtin_amdgcn_mfma_f32_16x16x32_bf16(pu[g2].v, vf[dg][g2], acc[dg], 0, 0, 0);
      __builtin_amdgcn_s_setprio(0);
    }

    __builtin_amdgcn_s_barrier();            // all waves done reading buf[cur]
    cur ^= 1;
  }

  // epilogue
#pragma unroll
  for (int r = 0; r < 4; ++r) {
    int row = wbase + kg * 4 + r;
    float inv = 1.0f / l[r];
#pragma unroll
    for (int dg = 0; dg < 5; ++dg)
      attn_out[(size_t)row * DM + h * HDIM + dg * 16 + r15] = f2bf(acc[dg][r] * inv);
  }
}

extern "C" void kernel_launch(void* const* d_in, const int* in_sizes, int n_in,
                              void* d_out, int out_size, void* d_ws, size_t ws_size,
                              hipStream_t stream) {
  const float* hidden = (const float*)d_in[0];
  const float* cosb = (const float*)d_in[1];
  const float* sinb = (const float*)d_in[2];
  const float* qkv_w = (const float*)d_in[3];
  const float* qkv_b = (const float*)d_in[4];
  const float* proj_w = (const float*)d_in[5];
  const float* proj_b = (const float*)d_in[6];
  const int* cu = (const int*)d_in[7];
  int nseg = in_sizes[7] - 1;
  float* out = (float*)d_out;

  char* ws = (char*)d_ws;
  unsigned short* Ah = (unsigned short*)(ws);                        // 10,485,760 B
  unsigned short* Wq = (unsigned short*)(ws + 10485760);             //  9,830,400 B
  unsigned short* Wp = (unsigned short*)(ws + 10485760 + 9830400);   //  3,276,800 B
  unsigned short* qkvB = (unsigned short*)(ws + 23592960);           // 31,457,280 B
  unsigned short* Vt = (unsigned short*)(ws + 23592960 + 31457280);  // 10,485,760 B
  unsigned short* attn_out = Ah;  // reuse (Ah dead after GEMM1)

  cvt_all<<<dim3(11520), dim3(256), 0, stream>>>(hidden, qkv_w, proj_w, Ah, Wq, Wp);
  gemm_bt2<1><<<dim3(480), dim3(512), 0, stream>>>(Ah, Wq, qkv_b, qkvB, SQ, N_QKV, DM, 30);
  rope_v_kernel<<<dim3(64, NH), dim3(256), 0, stream>>>(qkvB, cosb, sinb, Vt);
  attn_kernel<<<dim3(1024), dim3(256), 0, stream>>>(qkvB, Vt, cu, nseg, attn_out);
  gemm_bt2<0><<<dim3(160), dim3(512), 0, stream>>>(attn_out, Wp, proj_b, out, SQ, DM, DM, 10);
}